// Round 6
// baseline (80.409 us; speedup 1.0000x reference)
//
#include <hip/hip_runtime.h>

// Bahdanau attention, fused. query [8][400][256], y [8][400][256],
// Wq_w [128][256], Wq_b [128], Wy_w [128][256], Wy_b [128], v_w [1][128],
// v_b (dropped: softmax shift-invariant), n_wins_y [8] i32. out [8][400][256] f32.
// score = sum_a v_a*tanh(qp+yp) ~ sum_a (-2 v_a)/(e^{2x}+1) + const (dropped).
// qp/yp prescaled by 2*log2(e). One rcp per 4 elems (reciprocal-of-product).
//
// R4 lesson: dynamic register-array indexing -> scratch (280MB). All register
// arrays constant-indexed in fully-unrolled constant-trip loops; prefetch in
// NAMED registers. R5: apply phase lane<->(q,d4) mapping (8x less LDS read,
// no readlane chain, p via transposed stride-9 s_p); proj d-split (2x waves).

#define LOG2E 1.4426950408889634f
#define TANH_SCALE 2.8853900817779268f  // 2*log2(e)

constexpr int TQn = 400, TYn = 400, AD = 128, DD = 256;
constexpr int QT = 8;              // queries per fused block (1 wave each)
constexpr int QBLOCKS = TQn / QT;  // 50
constexpr int YT = 64;             // score tile rows
constexpr int AT = 32;             // apply tile rows
constexpr int SSTR = 65;           // score LDS row stride in float4 (transposed)
constexpr int PSTR = 9;            // s_p row stride in floats ([t][q], 9 coprime 32)

// ---------------- projection: qp' = (query@WqT + bq)*S ; yp' likewise ----------
__global__ __launch_bounds__(256, 4) void proj_kernel(
    const float* __restrict__ qin, const float* __restrict__ yin,
    const float* __restrict__ Wq, const float* __restrict__ bq,
    const float* __restrict__ Wy, const float* __restrict__ by,
    float* __restrict__ qp, float* __restrict__ yp)
{
    int blk = blockIdx.x;
    bool is_q = blk < 400;
    int row0 = (is_q ? blk : blk - 400) * 8;
    const float* in   = (is_q ? qin : yin) + (size_t)row0 * DD;
    const float* W    = is_q ? Wq : Wy;
    const float* bias = is_q ? bq : by;
    float* outp = (is_q ? qp : yp) + (size_t)row0 * AD;

    __shared__ float lin[8 * DD];      // 8 KB
    __shared__ float red[8][128];      // 4 KB (h=1 partial sums)
    {
        const float4* in4 = reinterpret_cast<const float4*>(in);
        float4* l4s = reinterpret_cast<float4*>(lin);
        for (int j = threadIdx.x; j < 8 * DD / 4; j += 256) l4s[j] = in4[j];
    }
    __syncthreads();

    const int a = threadIdx.x & 127;   // attention dim
    const int h = threadIdx.x >> 7;    // d-half: 0 -> d[0,128), 1 -> d[128,256)
    float acc[8] = {0.f,0.f,0.f,0.f,0.f,0.f,0.f,0.f};
    const float4* w4p = reinterpret_cast<const float4*>(W + (size_t)a * DD) + h * 32;
    const float4* l4  = reinterpret_cast<const float4*>(lin) + h * 32;
    #pragma unroll 4
    for (int d4 = 0; d4 < 32; ++d4) {
        float4 w4 = w4p[d4];
        #pragma unroll
        for (int r = 0; r < 8; ++r) {
            float4 v = l4[r * 64 + d4];  // wave-uniform broadcast
            acc[r] = fmaf(w4.x, v.x, acc[r]);
            acc[r] = fmaf(w4.y, v.y, acc[r]);
            acc[r] = fmaf(w4.z, v.z, acc[r]);
            acc[r] = fmaf(w4.w, v.w, acc[r]);
        }
    }
    if (h) {
        #pragma unroll
        for (int r = 0; r < 8; ++r) red[r][a] = acc[r];
    }
    __syncthreads();
    if (!h) {
        float bb = bias[a];
        #pragma unroll
        for (int r = 0; r < 8; ++r)
            outp[(size_t)r * AD + a] = (acc[r] + red[r][a] + bb) * TANH_SCALE;
    }
}

// ---------------- fused scores -> masked softmax -> att @ y --------------------
__global__ __launch_bounds__(512, 4) void fused_kernel(
    const float* __restrict__ y,    // [B][TY][DD]
    const float* __restrict__ qp,   // [B*TQ][AD] prescaled
    const float* __restrict__ yp,   // [B*TY][AD] prescaled
    const float* __restrict__ vw,   // [AD]
    const int*  __restrict__ nwins, // [B]
    float* __restrict__ out)        // [B][TQ][DD]
{
    __shared__ float4 s_qp4[QT * 32];       // 4 KB
    __shared__ float4 s_v4[32];             // 0.5 KB (holds -2*v)
    __shared__ float4 s_buf4[32 * SSTR];    // 33.3 KB: yp^T tile / y tile
    __shared__ float  s_p[448 * PSTR];      // 16.1 KB: p[t][q], stride 9

    const int b  = blockIdx.x / QBLOCKS;
    const int q0 = (blockIdx.x % QBLOCKS) * QT;
    const int tid = threadIdx.x;  // 0..511
    const int wave = tid >> 6;    // score: local query 0..7; apply: d-range
    const int lane = tid & 63;
    const int n = nwins[b];
    const float NEG_INF = -__builtin_inff();

    const float4* ypb = reinterpret_cast<const float4*>(yp);  // rows [3200][32]f4
    const float4* yb  = reinterpret_cast<const float4*>(y);   // rows [3200][64]f4

    // score staging coords: col pcol (a4), rows prow+16k
    const int pcol = tid & 31;
    const int prow = tid >> 5;    // 0..15
    // apply staging coords: col acol (d4), rows arow+8k
    const int acol = tid & 63;
    const int arow = tid >> 6;    // 0..7

    // named prefetch registers (never an indexable array -> cannot hit scratch)
    float4 p0, p1, p2, p3;

    // prefetch score tile 0 (rows 0..63 valid: n >= 200)
    {
        const size_t base = (size_t)(b * TYn) * 32 + pcol;
        p0 = ypb[base + (size_t)(prow +  0) * 32];
        p1 = ypb[base + (size_t)(prow + 16) * 32];
        p2 = ypb[base + (size_t)(prow + 32) * 32];
        p3 = ypb[base + (size_t)(prow + 48) * 32];
    }

    // stage qp tile + (-2*v); visible after first barrier
    if (tid < QT * 32) {
        s_qp4[tid] = reinterpret_cast<const float4*>(qp + (size_t)(b * TQn + q0) * AD)[tid];
    } else if (tid < QT * 32 + 32) {
        float4 v = reinterpret_cast<const float4*>(vw)[tid - QT * 32];
        s_v4[tid - QT * 32] = make_float4(-2.f * v.x, -2.f * v.y, -2.f * v.z, -2.f * v.w);
    }

    float sc[7];
    #pragma unroll
    for (int j = 0; j < 7; ++j) sc[j] = NEG_INF;

    const int ntile = (n + YT - 1) >> 6;  // 4..7, block-uniform

    // ---- score phase: constant-trip loop, uniform guard (no dynamic sc index) ----
    #pragma unroll
    for (int i = 0; i < 7; ++i) {
        if (i < ntile) {
            __syncthreads();  // all waves done reading s_buf4 (covers qp/v on i==0)
            s_buf4[pcol * SSTR + prow +  0] = p0;  // transposed store
            s_buf4[pcol * SSTR + prow + 16] = p1;
            s_buf4[pcol * SSTR + prow + 32] = p2;
            s_buf4[pcol * SSTR + prow + 48] = p3;
            if (i + 1 < ntile) {
                const int t0n = (i + 1) * YT;
                const size_t base = (size_t)(b * TYn) * 32 + pcol;
                int r0 = min(t0n + prow +  0, TYn - 1);
                int r1 = min(t0n + prow + 16, TYn - 1);
                int r2 = min(t0n + prow + 32, TYn - 1);
                int r3 = min(t0n + prow + 48, TYn - 1);
                p0 = ypb[base + (size_t)r0 * 32];  // in flight during compute
                p1 = ypb[base + (size_t)r1 * 32];
                p2 = ypb[base + (size_t)r2 * 32];
                p3 = ypb[base + (size_t)r3 * 32];
            }
            __syncthreads();
            float ac0 = 0.f, ac1 = 0.f, ac2 = 0.f, ac3 = 0.f;
            const float4* qrow = s_qp4 + wave * 32;
            #pragma unroll 8
            for (int a4 = 0; a4 < 32; ++a4) {
                float4 yv = s_buf4[a4 * SSTR + lane];  // contiguous 64-lane sweep
                float4 qv = qrow[a4];                  // wave-uniform broadcast
                float4 vv = s_v4[a4];                  // broadcast (-2v)
                float e0 = __builtin_amdgcn_exp2f(qv.x + yv.x);
                float e1 = __builtin_amdgcn_exp2f(qv.y + yv.y);
                float e2 = __builtin_amdgcn_exp2f(qv.z + yv.z);
                float e3 = __builtin_amdgcn_exp2f(qv.w + yv.w);
                float a0 = e0 + 1.f, a1 = e1 + 1.f, a2 = e2 + 1.f, a3 = e3 + 1.f;
                float p01 = a0 * a1, p23 = a2 * a3;
                float R = __builtin_amdgcn_rcpf(p01 * p23);
                float u = p23 * R, v = p01 * R;        // u=1/p01, v=1/p23
                ac0 = fmaf(vv.x, a1 * u, ac0);
                ac1 = fmaf(vv.y, a0 * u, ac1);
                ac2 = fmaf(vv.z, a3 * v, ac2);
                ac3 = fmaf(vv.w, a2 * v, ac3);
            }
            sc[i] = (ac0 + ac1) + (ac2 + ac3);  // garbage rows masked below
        }
    }

    // prefetch apply tile 0 (rows 0..31 valid: n >= 200); overlaps softmax
    {
        const size_t base = (size_t)(b * TYn) * 64 + acol;
        p0 = yb[base + (size_t)(arow +  0) * 64];
        p1 = yb[base + (size_t)(arow +  8) * 64];
        p2 = yb[base + (size_t)(arow + 16) * 64];
        p3 = yb[base + (size_t)(arow + 24) * 64];
    }

    // ---- mask + softmax over t (full 64-lane wave per q=wave) ----
    #pragma unroll
    for (int j = 0; j < 7; ++j) {
        int t = j * YT + lane;
        if (t >= n) sc[j] = NEG_INF;  // overwrites any garbage
    }
    float m = sc[0];
    #pragma unroll
    for (int j = 1; j < 7; ++j) m = fmaxf(m, sc[j]);
    #pragma unroll
    for (int off = 32; off >= 1; off >>= 1) m = fmaxf(m, __shfl_xor(m, off, 64));
    float l = 0.f;
    #pragma unroll
    for (int j = 0; j < 7; ++j) {
        float pv = __builtin_amdgcn_exp2f((sc[j] - m) * LOG2E);  // exp2(-inf)=0
        sc[j] = pv;
        l += pv;
    }
    #pragma unroll
    for (int off = 32; off >= 1; off >>= 1) l += __shfl_xor(l, off, 64);
    float inv = 1.0f / l;
    // publish p transposed: p[t][q], stride 9 (conflict-free both directions)
    #pragma unroll
    for (int j = 0; j < 7; ++j)
        s_p[(j * YT + lane) * PSTR + wave] = sc[j] * inv;  // t up to 447, 0 beyond n

    // ---- apply phase: lane <-> (q, d4): q = lane>>3, cols wave*8 + (lane&7) ----
    const int q  = lane >> 3;
    const int c4 = (wave << 3) + (lane & 7);  // this lane's float4 column 0..63
    float4 acc = {0.f, 0.f, 0.f, 0.f};
    const int natile = (n + AT - 1) / AT;  // 7..13, block-uniform
    for (int tile = 0; tile < natile; ++tile) {
        __syncthreads();  // prior consumers of s_buf4 done; covers s_p on tile 0
        s_buf4[(arow +  0) * 64 + acol] = p0;
        s_buf4[(arow +  8) * 64 + acol] = p1;
        s_buf4[(arow + 16) * 64 + acol] = p2;
        s_buf4[(arow + 24) * 64 + acol] = p3;
        if (tile + 1 < natile) {
            const int t0n = (tile + 1) * AT;
            const size_t base = (size_t)(b * TYn) * 64 + acol;
            int r0 = min(t0n + arow +  0, TYn - 1);
            int r1 = min(t0n + arow +  8, TYn - 1);
            int r2 = min(t0n + arow + 16, TYn - 1);
            int r3 = min(t0n + arow + 24, TYn - 1);
            p0 = yb[base + (size_t)r0 * 64];  // in flight during compute
            p1 = yb[base + (size_t)r1 * 64];
            p2 = yb[base + (size_t)r2 * 64];
            p3 = yb[base + (size_t)r3 * 64];
        }
        __syncthreads();
        const int tb = tile * AT;
        #pragma unroll 8
        for (int ttl = 0; ttl < AT; ++ttl) {
            float pt  = s_p[(tb + ttl) * PSTR + q];       // 8-addr broadcast
            float4 yv = s_buf4[ttl * 64 + c4];            // 8-addr broadcast (128B)
            acc.x = fmaf(pt, yv.x, acc.x);
            acc.y = fmaf(pt, yv.y, acc.y);
            acc.z = fmaf(pt, yv.z, acc.z);
            acc.w = fmaf(pt, yv.w, acc.w);
        }
    }
    // out[b][q0+q][c4*4 .. +3]
    reinterpret_cast<float4*>(out)[(size_t)(b * TQn + q0 + q) * 64 + c4] = acc;
}

extern "C" void kernel_launch(void* const* d_in, const int* in_sizes, int n_in,
                              void* d_out, int out_size, void* d_ws, size_t ws_size,
                              hipStream_t stream) {
    const float* query = (const float*)d_in[0];
    const float* y     = (const float*)d_in[1];
    const float* Wq_w  = (const float*)d_in[2];
    const float* Wq_b  = (const float*)d_in[3];
    const float* Wy_w  = (const float*)d_in[4];
    const float* Wy_b  = (const float*)d_in[5];
    const float* v_w   = (const float*)d_in[6];
    // d_in[7] = v_b: softmax-invariant, dropped.
    const int* nw      = (const int*)d_in[8];
    float* out = (float*)d_out;

    float* qp = (float*)d_ws;                    // [3200][128]
    float* yp = qp + (size_t)8 * 400 * 128;      // [3200][128]

    proj_kernel<<<800, 256, 0, stream>>>(query, y, Wq_w, Wq_b, Wy_w, Wy_b, qp, yp);
    fused_kernel<<<8 * QBLOCKS, 512, 0, stream>>>(y, qp, yp, v_w, nw, out);
}

// Round 7
// 75.301 us; speedup vs baseline: 1.0678x; 1.0678x over previous
//
#include <hip/hip_runtime.h>

// Bahdanau attention. query [8][400][256], y [8][400][256], Wq_w [128][256],
// Wq_b [128], Wy_w [128][256], Wy_b [128], v_w [1][128], v_b (dropped:
// softmax shift-invariant), n_wins_y [8] i32. out [8][400][256] f32.
//
// Identity: v.tanh(qp+yp) = const - sum_a 2 v_a/(e^{2(qp+yp)}+1); and
// e^{2(qp+yp)} = Eq*Ey with Eq,Ey precomputed -> score inner loop has NO
// transcendentals: a = fma(Eq,Ey,1) per element + one rcp per 4 elements.
//
// K1 proj: Eq = exp(2(Wq q + bq)), Ey likewise. 1600 blocks x 128.
// K2 score: grid (8 b x 50 qtile x 7 ttile) = 2800 blocks, one 64-t tile per
//           block, no loop barriers, early-exit t0>=n. Writes raw s.
// K3 apply: softmax(s) per wave + double-buffered 16-t y tiles, 1 barrier/tile.
//
// R4 lesson kept: no dynamically-indexed register arrays anywhere.

#define LOG2E 1.4426950408889634f
#define TANH_SCALE 2.8853900817779268f  // 2*log2(e)

constexpr int TQn = 400, TYn = 400, AD = 128, DD = 256;
constexpr int QT = 8;               // q per score block
constexpr int QBLOCKS = TQn / QT;   // 50
constexpr int YT = 64;              // t per score block
constexpr int NTT = 7;              // ceil(400/64)
constexpr int SSTR = 65;            // Ey^T tile stride (float4), conflict-free
constexpr int AQT = 8;              // q per apply block
constexpr int AT3 = 16;             // t per apply tile
constexpr int PSTR = 449;           // s_p row stride floats (449%32=1)

// ---------------- K1: Eq = exp(2(Wq q + b)); Ey likewise -----------------
__global__ __launch_bounds__(128, 4) void proj_kernel(
    const float* __restrict__ qin, const float* __restrict__ yin,
    const float* __restrict__ Wq, const float* __restrict__ bq,
    const float* __restrict__ Wy, const float* __restrict__ by,
    float* __restrict__ Eq, float* __restrict__ Ey)
{
    const int blk = blockIdx.x;           // [0,800) q-rows, [800,1600) y-rows
    const bool is_q = blk < 800;
    const int row0 = (is_q ? blk : blk - 800) * 4;
    const float* in   = (is_q ? qin : yin) + (size_t)row0 * DD;
    const float* W    = is_q ? Wq : Wy;
    const float* bias = is_q ? bq : by;
    float* outp = (is_q ? Eq : Ey) + (size_t)row0 * AD;

    __shared__ float lin[4 * DD];  // 4 KB
    {
        const float4* in4 = reinterpret_cast<const float4*>(in);
        float4* l4s = reinterpret_cast<float4*>(lin);
        l4s[threadIdx.x]       = in4[threadIdx.x];
        l4s[threadIdx.x + 128] = in4[threadIdx.x + 128];
    }
    __syncthreads();

    const int a = threadIdx.x;  // 0..127
    float acc0 = 0.f, acc1 = 0.f, acc2 = 0.f, acc3 = 0.f;
    const float4* w4p = reinterpret_cast<const float4*>(W + (size_t)a * DD);
    const float4* l4  = reinterpret_cast<const float4*>(lin);
    #pragma unroll 8
    for (int d4 = 0; d4 < 64; ++d4) {
        float4 w4 = w4p[d4];
        float4 v0 = l4[d4], v1 = l4[64 + d4], v2 = l4[128 + d4], v3 = l4[192 + d4];
        acc0 = fmaf(w4.x, v0.x, acc0); acc0 = fmaf(w4.y, v0.y, acc0);
        acc0 = fmaf(w4.z, v0.z, acc0); acc0 = fmaf(w4.w, v0.w, acc0);
        acc1 = fmaf(w4.x, v1.x, acc1); acc1 = fmaf(w4.y, v1.y, acc1);
        acc1 = fmaf(w4.z, v1.z, acc1); acc1 = fmaf(w4.w, v1.w, acc1);
        acc2 = fmaf(w4.x, v2.x, acc2); acc2 = fmaf(w4.y, v2.y, acc2);
        acc2 = fmaf(w4.z, v2.z, acc2); acc2 = fmaf(w4.w, v2.w, acc2);
        acc3 = fmaf(w4.x, v3.x, acc3); acc3 = fmaf(w4.y, v3.y, acc3);
        acc3 = fmaf(w4.z, v3.z, acc3); acc3 = fmaf(w4.w, v3.w, acc3);
    }
    const float bb = bias[a];
    outp[(size_t)0 * AD + a] = __builtin_amdgcn_exp2f((acc0 + bb) * TANH_SCALE);
    outp[(size_t)1 * AD + a] = __builtin_amdgcn_exp2f((acc1 + bb) * TANH_SCALE);
    outp[(size_t)2 * AD + a] = __builtin_amdgcn_exp2f((acc2 + bb) * TANH_SCALE);
    outp[(size_t)3 * AD + a] = __builtin_amdgcn_exp2f((acc3 + bb) * TANH_SCALE);
}

// ---------------- K2: raw scores, one (8q x 64t) tile per block -----------
__global__ __launch_bounds__(512, 2) void score_kernel(
    const float* __restrict__ Eq,   // [B*TQ][AD]
    const float* __restrict__ Ey,   // [B*TY][AD]
    const float* __restrict__ vw,   // [AD]
    const int*  __restrict__ nwins, // [B]
    float* __restrict__ s)          // [B][TQ][TY]
{
    const int bid = blockIdx.x;
    const int b   = bid / (QBLOCKS * NTT);
    const int rem = bid % (QBLOCKS * NTT);
    const int qt  = rem / NTT;
    const int tt  = rem % NTT;
    const int n   = nwins[b];
    const int t0  = tt * YT;
    if (t0 >= n) return;              // block-uniform early exit (~26% of blocks)
    const int q0 = qt * QT;

    __shared__ float4 s_eq[QT * 32];     // 4 KB
    __shared__ float4 s_v4[32];          // 0.5 KB (-2*v)
    __shared__ float4 s_ey[32 * SSTR];   // 33.3 KB, Ey tile transposed [a4][t]

    const int tid  = threadIdx.x;  // 0..511
    const int wave = tid >> 6;     // local q
    const int lane = tid & 63;     // t within tile
    const int pcol = tid & 31;     // a4
    const int prow = tid >> 5;     // 0..15

    {
        const float4* eyb = reinterpret_cast<const float4*>(Ey);
        const size_t base = (size_t)(b * TYn) * 32 + pcol;
        const int r1 = min(t0 + prow + 16, TYn - 1);
        const int r2 = min(t0 + prow + 32, TYn - 1);
        const int r3 = min(t0 + prow + 48, TYn - 1);
        s_ey[pcol * SSTR + prow     ] = eyb[base + (size_t)(t0 + prow) * 32];
        s_ey[pcol * SSTR + prow + 16] = eyb[base + (size_t)r1 * 32];
        s_ey[pcol * SSTR + prow + 32] = eyb[base + (size_t)r2 * 32];
        s_ey[pcol * SSTR + prow + 48] = eyb[base + (size_t)r3 * 32];
    }
    if (tid < QT * 32) {
        s_eq[tid] = reinterpret_cast<const float4*>(Eq + (size_t)(b * TQn + q0) * AD)[tid];
    } else if (tid < QT * 32 + 32) {
        float4 v = reinterpret_cast<const float4*>(vw)[tid - QT * 32];
        s_v4[tid - QT * 32] = make_float4(-2.f * v.x, -2.f * v.y, -2.f * v.z, -2.f * v.w);
    }
    __syncthreads();

    float ac0 = 0.f, ac1 = 0.f, ac2 = 0.f, ac3 = 0.f;
    const float4* qrow = s_eq + wave * 32;
    #pragma unroll 8
    for (int a4 = 0; a4 < 32; ++a4) {
        float4 yv = s_ey[a4 * SSTR + lane];  // contiguous 64-lane sweep (1 KB)
        float4 qv = qrow[a4];                // wave-uniform broadcast
        float4 vv = s_v4[a4];                // broadcast (-2v)
        // a = e^{2(qp+yp)} + 1 in ONE fma: a = Eq*Ey + 1
        float a0 = fmaf(qv.x, yv.x, 1.f);
        float a1 = fmaf(qv.y, yv.y, 1.f);
        float a2 = fmaf(qv.z, yv.z, 1.f);
        float a3 = fmaf(qv.w, yv.w, 1.f);
        float p01 = a0 * a1, p23 = a2 * a3;
        float R = __builtin_amdgcn_rcpf(p01 * p23);
        float u = p23 * R, v = p01 * R;      // u=1/p01, v=1/p23
        ac0 = fmaf(vv.x, a1 * u, ac0);
        ac1 = fmaf(vv.y, a0 * u, ac1);
        ac2 = fmaf(vv.z, a3 * v, ac2);
        ac3 = fmaf(vv.w, a2 * v, ac3);
    }
    const int t = t0 + lane;
    if (t < TYn)
        s[(size_t)(b * TQn + q0 + wave) * TYn + t] = (ac0 + ac1) + (ac2 + ac3);
}

// ---------------- K3: softmax + att@y (double-buffered y tiles) -----------
__global__ __launch_bounds__(512, 2) void apply_kernel(
    const float* __restrict__ y,    // [B][TY][DD]
    const float* __restrict__ s,    // [B][TQ][TY]
    const int*  __restrict__ nwins, // [B]
    float* __restrict__ out)        // [B][TQ][DD]
{
    const int bid = blockIdx.x;
    const int b   = bid / QBLOCKS;
    const int q0  = (bid % QBLOCKS) * AQT;
    const int tid = threadIdx.x, wave = tid >> 6, lane = tid & 63;
    const int n = nwins[b];
    const float NEG_INF = -__builtin_inff();

    __shared__ float  s_p[AQT][PSTR];     // 14.4 KB, p rows (0 beyond n)
    __shared__ float4 s_y[2][AT3 * 64];   // 32 KB double-buffered y tiles

    // ---- softmax for q = q0 + wave (full 64-lane wave) ----
    const float* srow = s + (size_t)(b * TQn + q0 + wave) * TYn;
    float sc0, sc1, sc2, sc3, sc4, sc5, sc6;
    {
        int t;
        t = 0 * 64 + lane; sc0 = (t < n) ? srow[t] : NEG_INF;
        t = 1 * 64 + lane; sc1 = (t < n) ? srow[t] : NEG_INF;
        t = 2 * 64 + lane; sc2 = (t < n) ? srow[t] : NEG_INF;
        t = 3 * 64 + lane; sc3 = (t < n) ? srow[t] : NEG_INF;
        t = 4 * 64 + lane; sc4 = (t < n) ? srow[t] : NEG_INF;
        t = 5 * 64 + lane; sc5 = (t < n) ? srow[t] : NEG_INF;
        t = 6 * 64 + lane; sc6 = (t < n) ? srow[t] : NEG_INF;
    }
    float m = fmaxf(fmaxf(fmaxf(sc0, sc1), fmaxf(sc2, sc3)),
                    fmaxf(fmaxf(sc4, sc5), sc6));
    #pragma unroll
    for (int off = 32; off >= 1; off >>= 1) m = fmaxf(m, __shfl_xor(m, off, 64));
    sc0 = __builtin_amdgcn_exp2f((sc0 - m) * LOG2E);
    sc1 = __builtin_amdgcn_exp2f((sc1 - m) * LOG2E);
    sc2 = __builtin_amdgcn_exp2f((sc2 - m) * LOG2E);
    sc3 = __builtin_amdgcn_exp2f((sc3 - m) * LOG2E);
    sc4 = __builtin_amdgcn_exp2f((sc4 - m) * LOG2E);
    sc5 = __builtin_amdgcn_exp2f((sc5 - m) * LOG2E);
    sc6 = __builtin_amdgcn_exp2f((sc6 - m) * LOG2E);
    float l = ((sc0 + sc1) + (sc2 + sc3)) + ((sc4 + sc5) + sc6);
    #pragma unroll
    for (int off = 32; off >= 1; off >>= 1) l += __shfl_xor(l, off, 64);
    const float inv = 1.0f / l;
    s_p[wave][0 * 64 + lane] = sc0 * inv;   // exp2(-inf)=0 beyond n
    s_p[wave][1 * 64 + lane] = sc1 * inv;
    s_p[wave][2 * 64 + lane] = sc2 * inv;
    s_p[wave][3 * 64 + lane] = sc3 * inv;
    s_p[wave][4 * 64 + lane] = sc4 * inv;
    s_p[wave][5 * 64 + lane] = sc5 * inv;
    s_p[wave][6 * 64 + lane] = sc6 * inv;

    // ---- apply: wave -> (2 q, half d); lane -> (q parity, d4) ----
    const float4* yb = reinterpret_cast<const float4*>(y) + (size_t)(b * TYn) * 64;
    const int scol = tid & 63, srow0 = tid >> 6;  // staging coords
    float4 g0 = yb[(size_t)(srow0    ) * 64 + scol];
    float4 g1 = yb[(size_t)(srow0 + 8) * 64 + scol];

    const int qa = ((wave & 3) << 1) + (lane >> 5);    // 0..7
    const int d4 = ((wave >> 2) << 5) + (lane & 31);   // 0..63
    float4 acc = {0.f, 0.f, 0.f, 0.f};
    const int ntile = (n + AT3 - 1) / AT3;  // 13..25, block-uniform

    __syncthreads();  // s_p visible to all waves
    for (int i = 0; i < ntile; ++i) {
        float4* buf = s_y[i & 1];
        buf[srow0 * 64 + scol]       = g0;
        buf[(srow0 + 8) * 64 + scol] = g1;
        if (i + 1 < ntile) {
            const int t0n = (i + 1) * AT3;
            g0 = yb[(size_t)(t0n + srow0    ) * 64 + scol];  // in flight over compute
            g1 = yb[(size_t)(t0n + srow0 + 8) * 64 + scol];
        }
        __syncthreads();  // buf ready; prev reads of buf finished one barrier ago
        const int tb = i * AT3;
        #pragma unroll
        for (int ttl = 0; ttl < AT3; ++ttl) {
            float  pt = s_p[qa][tb + ttl];        // 2 addrs/wave
            float4 yv = buf[ttl * 64 + d4];       // 512B, 2-way broadcast (free)
            acc.x = fmaf(pt, yv.x, acc.x);
            acc.y = fmaf(pt, yv.y, acc.y);
            acc.z = fmaf(pt, yv.z, acc.z);
            acc.w = fmaf(pt, yv.w, acc.w);
        }
    }
    reinterpret_cast<float4*>(out)[(size_t)(b * TQn + q0 + qa) * 64 + d4] = acc;
}

extern "C" void kernel_launch(void* const* d_in, const int* in_sizes, int n_in,
                              void* d_out, int out_size, void* d_ws, size_t ws_size,
                              hipStream_t stream) {
    const float* query = (const float*)d_in[0];
    const float* y     = (const float*)d_in[1];
    const float* Wq_w  = (const float*)d_in[2];
    const float* Wq_b  = (const float*)d_in[3];
    const float* Wy_w  = (const float*)d_in[4];
    const float* Wy_b  = (const float*)d_in[5];
    const float* v_w   = (const float*)d_in[6];
    // d_in[7] = v_b: softmax-invariant, dropped.
    const int* nw      = (const int*)d_in[8];
    float* out = (float*)d_out;

    float* Eq = (float*)d_ws;                      // [3200][128] = 1.64 MB
    float* Ey = Eq + (size_t)8 * TQn * AD;         // [3200][128] = 1.64 MB
    float* s  = Ey + (size_t)8 * TYn * AD;         // [8][400][400] = 5.12 MB

    proj_kernel<<<1600, 128, 0, stream>>>(query, y, Wq_w, Wq_b, Wy_w, Wy_b, Eq, Ey);
    score_kernel<<<8 * QBLOCKS * NTT, 512, 0, stream>>>(Eq, Ey, v_w, nw, s);
    apply_kernel<<<8 * QBLOCKS, 512, 0, stream>>>(y, s, nw, out);
}

// Round 8
// 65.873 us; speedup vs baseline: 1.2207x; 1.1431x over previous
//
#include <hip/hip_runtime.h>

// Bahdanau attention. query [8][400][256], y [8][400][256], Wq_w [128][256],
// Wq_b [128], Wy_w [128][256], Wy_b [128], v_w [1][128], v_b (dropped:
// softmax shift-invariant), n_wins_y [8] i32. out [8][400][256] f32.
//
// score = sum_a v_a*tanh(qp+yp) ~ const - sum_a 2 v_a/(Eq_a*Ey_a + 1),
// Eq = e^{2 qp}, Ey = e^{2 yp} precomputed -> inner loop = 1 fma/elem + 1 rcp/4.
//
// K0: transpose W -> WT4[k4][a] (f4) so proj W-loads are lane-coalesced.
//     (R7 lesson: W[a][k] with a=lane is a 64-line scattered read -> ~17us proj.)
// K1: proj, 800 blocks x 256 (8 rows, d-halves, LDS reduce). VALU-bound.
// K2: score, one (4q x 64t) tile per block, 256 thr; thread holds 4 q-accs so
//     each Ey LDS read feeds 4x fma (LDS /4); a-quarter split + shfl_xor reduce.
// K3: apply, 800 blocks (4q); wave = d4-group, lane = (q,d4): y reads are
//     4-way-broadcast 256B; 1 barrier/tile double-buffer (proven R4 pattern).
// R4 lesson kept everywhere: no runtime-indexed register arrays.

#define LOG2E 1.4426950408889634f
#define TANH_SCALE 2.8853900817779268f  // 2*log2(e)

constexpr int TQn = 400, TYn = 400, AD = 128, DD = 256;
constexpr int SSTR = 65;   // Ey^T tile stride in float4

// ---------------- K0: WT4[k4][a] = W[a][4k4..4k4+3] ------------------------
__global__ __launch_bounds__(128) void transpose_kernel(
    const float* __restrict__ Wq, const float* __restrict__ Wy,
    float4* __restrict__ WTq, float4* __restrict__ WTy)
{
    const int k4 = blockIdx.x & 63;
    const bool isq = blockIdx.x < 64;
    const float4* src = reinterpret_cast<const float4*>(isq ? Wq : Wy);
    float4* dst = isq ? WTq : WTy;
    const int a = threadIdx.x;                 // 0..127
    dst[k4 * 128 + a] = src[a * 64 + k4];
}

// ---------------- K1: Eq = exp(2(Wq q + b)); Ey likewise -------------------
__global__ __launch_bounds__(256, 4) void proj_kernel(
    const float* __restrict__ qin, const float* __restrict__ yin,
    const float4* __restrict__ WTq, const float* __restrict__ bq,
    const float4* __restrict__ WTy, const float* __restrict__ by,
    float* __restrict__ Eq, float* __restrict__ Ey)
{
    const int blk = blockIdx.x;               // [0,400) q, [400,800) y
    const bool is_q = blk < 400;
    const int row0 = (is_q ? blk : blk - 400) * 8;
    const float* in   = (is_q ? qin : yin) + (size_t)row0 * DD;
    const float4* wt  = is_q ? WTq : WTy;     // [64 k4][128 a]
    const float* bias = is_q ? bq : by;
    float* outp = (is_q ? Eq : Ey) + (size_t)row0 * AD;

    __shared__ float lin[8 * DD];             // 8 KB
    __shared__ float red[8][AD];              // 4 KB
    {
        const float4* in4 = reinterpret_cast<const float4*>(in);
        float4* l4s = reinterpret_cast<float4*>(lin);
        l4s[threadIdx.x]       = in4[threadIdx.x];
        l4s[threadIdx.x + 256] = in4[threadIdx.x + 256];
    }
    __syncthreads();

    const int a = threadIdx.x & 127;
    const int h = threadIdx.x >> 7;           // k-half
    float acc[8] = {0.f,0.f,0.f,0.f,0.f,0.f,0.f,0.f};
    const float4* l4 = reinterpret_cast<const float4*>(lin);
    #pragma unroll 8
    for (int i = 0; i < 32; ++i) {
        const int k4 = h * 32 + i;
        float4 w4 = wt[k4 * 128 + a];         // coalesced: 64 lanes x 16B contig
        #pragma unroll
        for (int r = 0; r < 8; ++r) {
            float4 v = l4[r * 64 + k4];       // uniform broadcast
            acc[r] = fmaf(w4.x, v.x, acc[r]);
            acc[r] = fmaf(w4.y, v.y, acc[r]);
            acc[r] = fmaf(w4.z, v.z, acc[r]);
            acc[r] = fmaf(w4.w, v.w, acc[r]);
        }
    }
    if (h) {
        #pragma unroll
        for (int r = 0; r < 8; ++r) red[r][a] = acc[r];
    }
    __syncthreads();
    if (!h) {
        const float bb = bias[a];
        #pragma unroll
        for (int r = 0; r < 8; ++r)
            outp[(size_t)r * AD + a] =
                __builtin_amdgcn_exp2f((acc[r] + red[r][a] + bb) * TANH_SCALE);
    }
}

// ---------------- K2: raw scores, one (4q x 64t) tile per block ------------
__global__ __launch_bounds__(256, 4) void score_kernel(
    const float* __restrict__ Eq,   // [B*TQ][AD]
    const float* __restrict__ Ey,   // [B*TY][AD]
    const float* __restrict__ vw,   // [AD]
    const int*  __restrict__ nwins, // [B]
    float* __restrict__ s)          // [B][TQ][TY]
{
    const int bid = blockIdx.x;               // 8 * 100 * 7
    const int b   = bid / 700;
    const int rem = bid % 700;
    const int qg  = rem / 7;
    const int tt  = rem % 7;
    const int n   = nwins[b];
    const int t0  = tt * 64;
    if (t0 >= n) return;                      // block-uniform early exit
    const int q0 = qg * 4;

    __shared__ float4 s_ey[32 * SSTR];        // 33.3 KB, Ey^T [a4][t]
    __shared__ float4 s_eq4[4 * 32];          // 2 KB
    __shared__ float4 s_v4[32];               // 0.5 KB (-2v)

    const int tid  = threadIdx.x;             // 0..255
    const int pcol = tid & 31;                // a4
    const int prow = tid >> 5;                // 0..7
    {
        const float4* eyb = reinterpret_cast<const float4*>(Ey);
        const size_t base = (size_t)(b * TYn) * 32 + pcol;
        #pragma unroll
        for (int k = 0; k < 8; ++k) {
            const int rt = min(t0 + prow + 8 * k, TYn - 1);
            s_ey[pcol * SSTR + prow + 8 * k] = eyb[base + (size_t)rt * 32];
        }
    }
    if (tid < 128) {
        s_eq4[tid] = reinterpret_cast<const float4*>(Eq + (size_t)(b * TQn + q0) * AD)[tid];
    } else if (tid < 160) {
        float4 v = reinterpret_cast<const float4*>(vw)[tid - 128];
        s_v4[tid - 128] = make_float4(-2.f * v.x, -2.f * v.y, -2.f * v.z, -2.f * v.w);
    }
    __syncthreads();

    const int lane = tid & 63;
    const int wave = tid >> 6;                // t-subtile
    const int tloc = (wave << 4) | (lane & 15);
    const int ag   = lane >> 4;               // a-quarter
    float ac0 = 0.f, ac1 = 0.f, ac2 = 0.f, ac3 = 0.f;
    #pragma unroll
    for (int i = 0; i < 8; ++i) {
        const int a4 = ag * 8 + i;
        const float4 yv = s_ey[a4 * SSTR + tloc];
        const float4 vv = s_v4[a4];
        // 4 q's reuse this yv read (LDS traffic /4)
        #define SCORE_Q(ACC, QQ)                                            \
        {                                                                   \
            float4 qv = s_eq4[(QQ) * 32 + a4];                              \
            float a0 = fmaf(qv.x, yv.x, 1.f);                               \
            float a1 = fmaf(qv.y, yv.y, 1.f);                               \
            float a2 = fmaf(qv.z, yv.z, 1.f);                               \
            float a3 = fmaf(qv.w, yv.w, 1.f);                               \
            float p01 = a0 * a1, p23 = a2 * a3;                             \
            float R = __builtin_amdgcn_rcpf(p01 * p23);                     \
            float u = p23 * R, w = p01 * R;                                 \
            ACC = fmaf(vv.x, a1 * u, ACC);                                  \
            ACC = fmaf(vv.y, a0 * u, ACC);                                  \
            ACC = fmaf(vv.z, a3 * w, ACC);                                  \
            ACC = fmaf(vv.w, a2 * w, ACC);                                  \
        }
        SCORE_Q(ac0, 0) SCORE_Q(ac1, 1) SCORE_Q(ac2, 2) SCORE_Q(ac3, 3)
        #undef SCORE_Q
    }
    // combine a-quarters: xor16 (ag bit0), xor32 (ag bit1)
    ac0 += __shfl_xor(ac0, 16, 64); ac0 += __shfl_xor(ac0, 32, 64);
    ac1 += __shfl_xor(ac1, 16, 64); ac1 += __shfl_xor(ac1, 32, 64);
    ac2 += __shfl_xor(ac2, 16, 64); ac2 += __shfl_xor(ac2, 32, 64);
    ac3 += __shfl_xor(ac3, 16, 64); ac3 += __shfl_xor(ac3, 32, 64);
    const int t = t0 + tloc;
    if (ag == 0 && t < TYn) {
        const size_t o = (size_t)(b * TQn + q0) * TYn + t;
        s[o]            = ac0;
        s[o + TYn]      = ac1;
        s[o + 2 * TYn]  = ac2;
        s[o + 3 * TYn]  = ac3;
    }
}

// ---------------- K3: softmax + att@y (4 q per block, dbuf y tiles) --------
__global__ __launch_bounds__(256, 4) void apply_kernel(
    const float* __restrict__ y,    // [B][TY][DD]
    const float* __restrict__ s,    // [B][TQ][TY]
    const int*  __restrict__ nwins, // [B]
    float* __restrict__ out)        // [B][TQ][DD]
{
    const int bid = blockIdx.x;               // 8 * 100
    const int b   = bid / 100;
    const int q0  = (bid % 100) * 4;
    const int tid = threadIdx.x, wave = tid >> 6, lane = tid & 63;
    const int n = nwins[b];
    const float NEG_INF = -__builtin_inff();

    __shared__ float  s_p[4][408];            // 6.5 KB (p rows; 0 beyond n)
    __shared__ float4 s_y[2][16 * 64];        // 32 KB dbuf y tiles

    // prefetch y tile 0 early (overlaps softmax); rows 0..15 valid (n >= 200)
    const float4* yb = reinterpret_cast<const float4*>(y) + (size_t)(b * TYn) * 64;
    const int scol = tid & 63, srow0 = tid >> 6;   // staging coords (rows srow0+4k)
    float4 g0 = yb[(size_t)(srow0     ) * 64 + scol];
    float4 g1 = yb[(size_t)(srow0 +  4) * 64 + scol];
    float4 g2 = yb[(size_t)(srow0 +  8) * 64 + scol];
    float4 g3 = yb[(size_t)(srow0 + 12) * 64 + scol];

    // ---- softmax for q = q0 + wave (4 waves) ----
    const float* srow = s + (size_t)(b * TQn + q0 + wave) * TYn;
    float sc0, sc1, sc2, sc3, sc4, sc5, sc6;
    {
        int t;
        t = 0 * 64 + lane; sc0 = (t < n) ? srow[t] : NEG_INF;
        t = 1 * 64 + lane; sc1 = (t < n) ? srow[t] : NEG_INF;
        t = 2 * 64 + lane; sc2 = (t < n) ? srow[t] : NEG_INF;
        t = 3 * 64 + lane; sc3 = (t < n) ? srow[t] : NEG_INF;
        t = 4 * 64 + lane; sc4 = (t < n) ? srow[t] : NEG_INF;
        t = 5 * 64 + lane; sc5 = (t < n) ? srow[t] : NEG_INF;
        t = 6 * 64 + lane; sc6 = (t < n) ? srow[t] : NEG_INF;
    }
    float m = fmaxf(fmaxf(fmaxf(sc0, sc1), fmaxf(sc2, sc3)),
                    fmaxf(fmaxf(sc4, sc5), sc6));
    #pragma unroll
    for (int off = 32; off >= 1; off >>= 1) m = fmaxf(m, __shfl_xor(m, off, 64));
    sc0 = __builtin_amdgcn_exp2f((sc0 - m) * LOG2E);
    sc1 = __builtin_amdgcn_exp2f((sc1 - m) * LOG2E);
    sc2 = __builtin_amdgcn_exp2f((sc2 - m) * LOG2E);
    sc3 = __builtin_amdgcn_exp2f((sc3 - m) * LOG2E);
    sc4 = __builtin_amdgcn_exp2f((sc4 - m) * LOG2E);
    sc5 = __builtin_amdgcn_exp2f((sc5 - m) * LOG2E);
    sc6 = __builtin_amdgcn_exp2f((sc6 - m) * LOG2E);
    float l = ((sc0 + sc1) + (sc2 + sc3)) + ((sc4 + sc5) + sc6);
    #pragma unroll
    for (int off = 32; off >= 1; off >>= 1) l += __shfl_xor(l, off, 64);
    const float inv = 1.0f / l;
    s_p[wave][0 * 64 + lane] = sc0 * inv;
    s_p[wave][1 * 64 + lane] = sc1 * inv;
    s_p[wave][2 * 64 + lane] = sc2 * inv;
    s_p[wave][3 * 64 + lane] = sc3 * inv;
    s_p[wave][4 * 64 + lane] = sc4 * inv;
    s_p[wave][5 * 64 + lane] = sc5 * inv;
    {   // chunk 6: t up to 447 would overflow [408] -> guard (p beyond n unused)
        const int t = 6 * 64 + lane;
        if (t < TYn) s_p[wave][t] = sc6 * inv;
    }

    // ---- apply: wave = d4-group, lane = (q, d4i) -> 4-way broadcast reads ----
    const int q  = lane >> 4;                 // 0..3
    const int d4 = (wave << 4) | (lane & 15); // 0..63
    float4 acc = {0.f, 0.f, 0.f, 0.f};
    const int ntile = (n + 15) >> 4;          // 13..25, block-uniform

    __syncthreads();                          // s_p visible
    for (int i = 0; i < ntile; ++i) {
        float4* buf = s_y[i & 1];
        buf[(srow0     ) * 64 + scol] = g0;
        buf[(srow0 +  4) * 64 + scol] = g1;
        buf[(srow0 +  8) * 64 + scol] = g2;
        buf[(srow0 + 12) * 64 + scol] = g3;
        if (i + 1 < ntile) {
            const int t0n = (i + 1) * 16;     // rows <= 399 guaranteed
            g0 = yb[(size_t)(t0n + srow0     ) * 64 + scol];
            g1 = yb[(size_t)(t0n + srow0 +  4) * 64 + scol];
            g2 = yb[(size_t)(t0n + srow0 +  8) * 64 + scol];
            g3 = yb[(size_t)(t0n + srow0 + 12) * 64 + scol];
        }
        __syncthreads();  // buf ready; prior reads of this buf ended >=1 barrier ago
        const int tb = i * 16;
        #pragma unroll
        for (int ttl = 0; ttl < 16; ++ttl) {
            const float  pt = s_p[q][tb + ttl];     // 4 scalar broadcasts
            const float4 yv = buf[ttl * 64 + d4];   // 256B, 4-way broadcast
            acc.x = fmaf(pt, yv.x, acc.x);
            acc.y = fmaf(pt, yv.y, acc.y);
            acc.z = fmaf(pt, yv.z, acc.z);
            acc.w = fmaf(pt, yv.w, acc.w);
        }
    }
    reinterpret_cast<float4*>(out)[(size_t)(b * TQn + q0 + q) * 64 + d4] = acc;
}

extern "C" void kernel_launch(void* const* d_in, const int* in_sizes, int n_in,
                              void* d_out, int out_size, void* d_ws, size_t ws_size,
                              hipStream_t stream) {
    const float* query = (const float*)d_in[0];
    const float* y     = (const float*)d_in[1];
    const float* Wq_w  = (const float*)d_in[2];
    const float* Wq_b  = (const float*)d_in[3];
    const float* Wy_w  = (const float*)d_in[4];
    const float* Wy_b  = (const float*)d_in[5];
    const float* v_w   = (const float*)d_in[6];
    // d_in[7] = v_b: softmax-invariant, dropped.
    const int* nw      = (const int*)d_in[8];
    float* out = (float*)d_out;

    float4* WTq = (float4*)d_ws;                   // [64*128] f4 = 131 KB
    float4* WTy = WTq + 64 * 128;                  // 131 KB
    float*  Eq  = (float*)(WTy + 64 * 128);        // [3200][128] = 1.64 MB
    float*  Ey  = Eq + (size_t)8 * TQn * AD;       // 1.64 MB
    float*  s   = Ey + (size_t)8 * TYn * AD;       // [8][400][400] = 5.12 MB

    transpose_kernel<<<128, 128, 0, stream>>>(Wq_w, Wy_w, WTq, WTy);
    proj_kernel<<<800, 256, 0, stream>>>(query, y, WTq, Wq_b, WTy, Wy_b, Eq, Ey);
    score_kernel<<<8 * 100 * 7, 256, 0, stream>>>(Eq, Ey, v_w, nw, s);
    apply_kernel<<<8 * 100, 256, 0, stream>>>(y, s, nw, out);
}